// Round 1
// baseline (84.860 us; speedup 1.0000x reference)
//
#include <hip/hip_runtime.h>

typedef __attribute__((ext_vector_type(8))) short s16x8;
typedef __attribute__((ext_vector_type(4))) short s16x4;
typedef __attribute__((ext_vector_type(4))) float fx4;

#define DEVINL __device__ __forceinline__

constexpr int EMBED = 768;
constexpr int HD    = 64;
constexpr int NB    = 16;
constexpr int LEN   = 1024;
constexpr int M_TOT = NB * LEN; // 16384

// fp32 -> bf16 (RNE). Inputs here are well-behaved (no NaN/Inf).
DEVINL short f2bf(float f) {
  union { float f; unsigned u; } c; c.f = f;
  unsigned r = c.u + 0x7FFFu + ((c.u >> 16) & 1u);
  return (short)(r >> 16);
}

DEVINL fx4 mfma16(s16x8 a, s16x8 b, fx4 c) {
  return __builtin_amdgcn_mfma_f32_16x16x32_bf16(a, b, c, 0, 0, 0);
}

// ---------------------------------------------------------------------------
// Projection: Y[M,64] = bf16( X[M,768] @ W[64,768]^T + b )
// BM=64 rows/block, 4 waves, each wave 16 rows. BK=32 per step.
// LDS tiles padded to 40 shorts/row (80 B) -> ~2-way bank conflicts on b128.
// ---------------------------------------------------------------------------
__global__ __launch_bounds__(256) void proj_q_kernel(
    const float* __restrict__ X, const float* __restrict__ W,
    const float* __restrict__ bias, short* __restrict__ Y)
{
  __shared__ short Xs[64][40];
  __shared__ short Ws[64][40];
  const int t    = threadIdx.x;
  const int lane = t & 63;
  const int wv   = t >> 6;
  const int fr   = lane & 15;   // fragment row/col
  const int fg   = lane >> 4;   // k-group
  const int m0   = blockIdx.x * 64;

  fx4 acc[4];
#pragma unroll
  for (int c = 0; c < 4; ++c) acc[c] = fx4{0.f, 0.f, 0.f, 0.f};

  const int srow = t >> 2;        // 0..63
  const int scol = (t & 3) * 8;   // 0,8,16,24
  const float* xrow = X + (size_t)(m0 + srow) * EMBED + scol;
  const float* wrow = W + (size_t)srow * EMBED + scol;

  for (int k0 = 0; k0 < EMBED; k0 += 32) {
    fx4 xv0 = *reinterpret_cast<const fx4*>(xrow + k0);
    fx4 xv1 = *reinterpret_cast<const fx4*>(xrow + k0 + 4);
    fx4 wv0 = *reinterpret_cast<const fx4*>(wrow + k0);
    fx4 wv1 = *reinterpret_cast<const fx4*>(wrow + k0 + 4);
    s16x8 xb, wb;
#pragma unroll
    for (int j = 0; j < 4; ++j) {
      xb[j] = f2bf(xv0[j]); xb[j + 4] = f2bf(xv1[j]);
      wb[j] = f2bf(wv0[j]); wb[j + 4] = f2bf(wv1[j]);
    }
    __syncthreads();  // previous iteration's fragment reads done
    *reinterpret_cast<s16x8*>(&Xs[srow][scol]) = xb;
    *reinterpret_cast<s16x8*>(&Ws[srow][scol]) = wb;
    __syncthreads();
    s16x8 xa = *reinterpret_cast<const s16x8*>(&Xs[wv * 16 + fr][fg * 8]);
#pragma unroll
    for (int c = 0; c < 4; ++c) {
      s16x8 wf = *reinterpret_cast<const s16x8*>(&Ws[c * 16 + fr][fg * 8]);
      acc[c] = mfma16(xa, wf, acc[c]);
    }
  }
#pragma unroll
  for (int c = 0; c < 4; ++c) {
    const int d = c * 16 + fr;
    const float bv = bias[d];
#pragma unroll
    for (int r = 0; r < 4; ++r) {
      const int m = m0 + wv * 16 + fg * 4 + r;
      Y[(size_t)m * HD + d] = f2bf(acc[c][r] + bv);
    }
  }
}

// enc -> K [b,kv,64] bf16  and  V^T [b,64,kv] bf16 in one pass over enc.
__global__ __launch_bounds__(256) void proj_kv_kernel(
    const float* __restrict__ X,
    const float* __restrict__ Wk, const float* __restrict__ bk,
    const float* __restrict__ Wv, const float* __restrict__ bv,
    short* __restrict__ Kout, short* __restrict__ VT)
{
  __shared__ short Xs[64][40];
  __shared__ short Wks[64][40];
  __shared__ short Wvs[64][40];
  const int t    = threadIdx.x;
  const int lane = t & 63;
  const int wv   = t >> 6;
  const int fr   = lane & 15;
  const int fg   = lane >> 4;
  const int m0   = blockIdx.x * 64;

  fx4 kacc[4], vacc[4];
#pragma unroll
  for (int c = 0; c < 4; ++c) {
    kacc[c] = fx4{0.f, 0.f, 0.f, 0.f};
    vacc[c] = fx4{0.f, 0.f, 0.f, 0.f};
  }

  const int srow = t >> 2;
  const int scol = (t & 3) * 8;
  const float* xrow  = X  + (size_t)(m0 + srow) * EMBED + scol;
  const float* wkrow = Wk + (size_t)srow * EMBED + scol;
  const float* wvrow = Wv + (size_t)srow * EMBED + scol;

  for (int k0 = 0; k0 < EMBED; k0 += 32) {
    fx4 xv0 = *reinterpret_cast<const fx4*>(xrow + k0);
    fx4 xv1 = *reinterpret_cast<const fx4*>(xrow + k0 + 4);
    fx4 k0v = *reinterpret_cast<const fx4*>(wkrow + k0);
    fx4 k1v = *reinterpret_cast<const fx4*>(wkrow + k0 + 4);
    fx4 v0v = *reinterpret_cast<const fx4*>(wvrow + k0);
    fx4 v1v = *reinterpret_cast<const fx4*>(wvrow + k0 + 4);
    s16x8 xb, kb, vb;
#pragma unroll
    for (int j = 0; j < 4; ++j) {
      xb[j] = f2bf(xv0[j]); xb[j + 4] = f2bf(xv1[j]);
      kb[j] = f2bf(k0v[j]); kb[j + 4] = f2bf(k1v[j]);
      vb[j] = f2bf(v0v[j]); vb[j + 4] = f2bf(v1v[j]);
    }
    __syncthreads();
    *reinterpret_cast<s16x8*>(&Xs[srow][scol])  = xb;
    *reinterpret_cast<s16x8*>(&Wks[srow][scol]) = kb;
    *reinterpret_cast<s16x8*>(&Wvs[srow][scol]) = vb;
    __syncthreads();
    s16x8 xa = *reinterpret_cast<const s16x8*>(&Xs[wv * 16 + fr][fg * 8]);
#pragma unroll
    for (int c = 0; c < 4; ++c) {
      s16x8 wkf = *reinterpret_cast<const s16x8*>(&Wks[c * 16 + fr][fg * 8]);
      s16x8 wvf = *reinterpret_cast<const s16x8*>(&Wvs[c * 16 + fr][fg * 8]);
      kacc[c] = mfma16(xa, wkf, kacc[c]);
      vacc[c] = mfma16(xa, wvf, vacc[c]);
    }
  }
  const int bidx   = m0 >> 10;               // batch (64 | 1024, no straddle)
  const int kvbase = (m0 & 1023) + wv * 16 + fg * 4;
#pragma unroll
  for (int c = 0; c < 4; ++c) {
    const int d = c * 16 + fr;
    const float bkd = bk[d];
    const float bvd = bv[d];
    s16x4 vpack;
#pragma unroll
    for (int r = 0; r < 4; ++r) {
      const int m = m0 + wv * 16 + fg * 4 + r;
      Kout[(size_t)m * HD + d] = f2bf(kacc[c][r] + bkd);
      vpack[r] = f2bf(vacc[c][r] + bvd);
    }
    *reinterpret_cast<s16x4*>(VT + ((size_t)(bidx * HD + d) * LEN + kvbase)) = vpack;
  }
}

// ---------------------------------------------------------------------------
// Flash attention: 4 waves/block, each wave owns 16 q rows, KVBLK=32.
// K/V read directly from global (L2-resident: 256 KB/batch). P transposed
// from the MFMA D-layout to A-layout via a per-wave padded LDS tile
// (wave-internal: DS ops of one wave execute in order; no barrier needed).
// ---------------------------------------------------------------------------
__global__ __launch_bounds__(256) void attn_kernel(
    const short* __restrict__ Q, const short* __restrict__ K,
    const short* __restrict__ VT, float* __restrict__ Out)
{
  __shared__ short Plds[4][16][40];
  const int t    = threadIdx.x;
  const int lane = t & 63;
  const int wv   = t >> 6;
  const int fr   = lane & 15;
  const int fg   = lane >> 4;
  const int b    = blockIdx.x >> 4;
  const int q0   = (blockIdx.x & 15) * 64;
  const int qrow = q0 + wv * 16;

  const short* Qb  = Q  + (size_t)b * LEN * HD;
  const short* Kb  = K  + (size_t)b * LEN * HD;
  const short* VTb = VT + (size_t)b * HD * LEN;

  s16x8 qa0 = *reinterpret_cast<const s16x8*>(Qb + (size_t)(qrow + fr) * HD + fg * 8);
  s16x8 qa1 = *reinterpret_cast<const s16x8*>(Qb + (size_t)(qrow + fr) * HD + 32 + fg * 8);

  fx4 hacc[4];
#pragma unroll
  for (int c = 0; c < 4; ++c) hacc[c] = fx4{0.f, 0.f, 0.f, 0.f};
  float m[4], lsum[4];
#pragma unroll
  for (int r = 0; r < 4; ++r) { m[r] = -1e30f; lsum[r] = 0.f; }

  const float SC = 0.125f * 1.44269504088896340736f;  // into exp2 domain

  for (int kv0 = 0; kv0 < LEN; kv0 += 32) {
    // S = Q K^T for 32 kv cols, as two 16x16 fragments
    fx4 sacc[2];
#pragma unroll
    for (int s = 0; s < 2; ++s) {
      const short* kp = Kb + (size_t)(kv0 + s * 16 + fr) * HD + fg * 8;
      s16x8 kb0 = *reinterpret_cast<const s16x8*>(kp);
      s16x8 kb1 = *reinterpret_cast<const s16x8*>(kp + 32);
      fx4 z = fx4{0.f, 0.f, 0.f, 0.f};
      z = mfma16(qa0, kb0, z);
      sacc[s] = mfma16(qa1, kb1, z);
    }
    float x0[4], x1[4], rmax[4];
#pragma unroll
    for (int r = 0; r < 4; ++r) {
      x0[r] = sacc[0][r] * SC;
      x1[r] = sacc[1][r] * SC;
      rmax[r] = fmaxf(x0[r], x1[r]);
    }
#pragma unroll
    for (int d = 1; d < 16; d <<= 1)
#pragma unroll
      for (int r = 0; r < 4; ++r)
        rmax[r] = fmaxf(rmax[r], __shfl_xor(rmax[r], d, 64));
    float corr[4], rsum[4], p0[4], p1[4];
#pragma unroll
    for (int r = 0; r < 4; ++r) {
      float mn = fmaxf(m[r], rmax[r]);
      corr[r] = __builtin_amdgcn_exp2f(m[r] - mn);
      m[r] = mn;
      p0[r] = __builtin_amdgcn_exp2f(x0[r] - mn);
      p1[r] = __builtin_amdgcn_exp2f(x1[r] - mn);
      rsum[r] = p0[r] + p1[r];
    }
#pragma unroll
    for (int d = 1; d < 16; d <<= 1)
#pragma unroll
      for (int r = 0; r < 4; ++r)
        rsum[r] += __shfl_xor(rsum[r], d, 64);
#pragma unroll
    for (int r = 0; r < 4; ++r) lsum[r] = lsum[r] * corr[r] + rsum[r];
    // P (D-layout) -> LDS -> re-read in A-layout
#pragma unroll
    for (int r = 0; r < 4; ++r) {
      Plds[wv][fg * 4 + r][fr]      = f2bf(p0[r]);
      Plds[wv][fg * 4 + r][16 + fr] = f2bf(p1[r]);
    }
    __builtin_amdgcn_wave_barrier();
    s16x8 pa = *reinterpret_cast<const s16x8*>(&Plds[wv][fr][fg * 8]);
#pragma unroll
    for (int c = 0; c < 4; ++c) {
      fx4 h = hacc[c];
#pragma unroll
      for (int r = 0; r < 4; ++r) h[r] *= corr[r];
      s16x8 vb = *reinterpret_cast<const s16x8*>(
          VTb + (size_t)(c * 16 + fr) * LEN + kv0 + fg * 8);
      hacc[c] = mfma16(pa, vb, h);
    }
  }
  float* Ob = Out + (size_t)b * LEN * HD;
  float inv[4];
#pragma unroll
  for (int r = 0; r < 4; ++r) inv[r] = 1.0f / lsum[r];
#pragma unroll
  for (int c = 0; c < 4; ++c)
#pragma unroll
    for (int r = 0; r < 4; ++r)
      Ob[(size_t)(qrow + fg * 4 + r) * HD + c * 16 + fr] = hacc[c][r] * inv[r];
}

extern "C" void kernel_launch(void* const* d_in, const int* in_sizes, int n_in,
                              void* d_out, int out_size, void* d_ws, size_t ws_size,
                              hipStream_t stream) {
  const float* dec = (const float*)d_in[0];
  const float* enc = (const float*)d_in[1];
  const float* Wq  = (const float*)d_in[2];
  const float* bq  = (const float*)d_in[3];
  const float* Wk  = (const float*)d_in[4];
  const float* bk  = (const float*)d_in[5];
  const float* Wv  = (const float*)d_in[6];
  const float* bv  = (const float*)d_in[7];
  float* out = (float*)d_out;

  short* qws  = (short*)d_ws;                       // [16384,64] bf16 = 2 MB
  short* kws  = qws + (size_t)M_TOT * HD;           // [16384,64] bf16 = 2 MB
  short* vtws = kws + (size_t)M_TOT * HD;           // [16,64,1024] bf16 = 2 MB

  proj_q_kernel<<<M_TOT / 64, 256, 0, stream>>>(dec, Wq, bq, qws);
  proj_kv_kernel<<<M_TOT / 64, 256, 0, stream>>>(enc, Wk, bk, Wv, bv, kws, vtws);
  attn_kernel<<<NB * (LEN / 64), 256, 0, stream>>>(qws, kws, vtws, out);
}